// Round 11
// baseline (1615.739 us; speedup 1.0000x reference)
//
#include <hip/hip_runtime.h>
#include <hip/hip_bf16.h>

#define B 64
#define KDIM 196
#define H 512
#define V 10000
#define TSTEPS 30
#define VP 10240       // padded V: 320 strips * 32
#define NVC 40         // VP/256 chunks (base finish)
#define NSLOT 8
#define SLOTSTRIDE 16  // u64 per b -> 128B
#define NT 256

typedef unsigned long long u64;
typedef unsigned int u32;

__device__ __forceinline__ u64 pack_vi(float v, int idx) {
    u32 kb = __float_as_uint(v);
    kb = (kb & 0x80000000u) ? ~kb : (kb | 0x80000000u);
    return ((u64)kb << 32) | (u32)(~(u32)idx);
}
__device__ __forceinline__ u32 best_idx_of_slots(const u64* __restrict__ slots, int b) {
    u64 best = slots[b * SLOTSTRIDE];
#pragma unroll
    for (int s = 1; s < NSLOT; ++s) { u64 v = slots[b * SLOTSTRIDE + s]; if (v > best) best = v; }
    return ~(u32)best;
}

// ---------------- precompute kernels ----------------

__global__ void k_transpose_fc(const float* __restrict__ fcw, float* __restrict__ dst, int coloff) {
    __shared__ float tile[32][33];
    int v0 = blockIdx.x * 32, i0 = blockIdx.y * 32;
    int tx = threadIdx.x, ty = threadIdx.y;
#pragma unroll
    for (int r = 0; r < 32; r += 8) {
        int v = v0 + ty + r; int i = i0 + tx;
        tile[ty + r][tx] = (v < V) ? fcw[(size_t)v * 1024 + coloff + i] : 0.f;
    }
    __syncthreads();
#pragma unroll
    for (int r = 0; r < 32; r += 8) {
        int i = i0 + ty + r; int v = v0 + tx;
        dst[(size_t)i * VP + v] = tile[tx][ty + r];
    }
}

__global__ void k_build_wct(const float* __restrict__ wih, const float* __restrict__ whh,
                            float* __restrict__ dst) {
    __shared__ float tile[32][33];
    int j0 = blockIdx.x * 32, i0 = blockIdx.y * 32;
    int tx = threadIdx.x, ty = threadIdx.y;
#pragma unroll
    for (int r = 0; r < 32; r += 8) {
        int j = j0 + ty + r; int i = i0 + tx;
        tile[ty + r][tx] = (i < 512) ? wih[(size_t)j * 512 + i] : whh[(size_t)j * 512 + i - 512];
    }
    __syncthreads();
#pragma unroll
    for (int r = 0; r < 32; r += 8) {
        int i = i0 + ty + r; int j = j0 + tx;
        dst[(size_t)i * 2048 + j] = tile[tx][ty + r];
    }
}

// e partials over h-chunks: epart[(b*8+hc)][k]; grid (64 b, 8 hc)
__global__ void k_e_part(const float* __restrict__ iml, const float* __restrict__ attn_w,
                         float* __restrict__ epart) {
    int b = blockIdx.x, hc = blockIdx.y, t = threadIdx.x;
    __shared__ float wa[64];
    if (t < 64) wa[t] = attn_w[hc * 64 + t];
    __syncthreads();
    if (t < KDIM) {
        const float* p = iml + (size_t)b * 512 * KDIM + (size_t)hc * 64 * KDIM + t;
        float acc = 0.f;
#pragma unroll 8
        for (int h = 0; h < 64; ++h) acc += p[(size_t)h * KDIM] * wa[h];
        epart[(size_t)(b * 8 + hc) * 208 + t] = acc;
    }
}

// reduce 8 partials + softmax over k -> alpha. grid 64
__global__ void k_e_softmax(const float* __restrict__ epart, float* __restrict__ alpha) {
    int b = blockIdx.x, t = threadIdx.x;
    float acc = 0.f;
    if (t < KDIM) {
#pragma unroll
        for (int c = 0; c < 8; ++c) acc += epart[(size_t)(b * 8 + c) * 208 + t];
    }
    __shared__ float red[256];
    red[t] = (t < KDIM) ? acc : -__builtin_inff();
    __syncthreads();
    for (int s = 128; s; s >>= 1) { if (t < s) red[t] = fmaxf(red[t], red[t + s]); __syncthreads(); }
    float mx = red[0];
    __syncthreads();
    float ex = (t < KDIM) ? expf(acc - mx) : 0.f;
    red[t] = ex; __syncthreads();
    for (int s = 128; s; s >>= 1) { if (t < s) red[t] += red[t + s]; __syncthreads(); }
    if (t < KDIM) alpha[b * KDIM + t] = ex / red[0];
}

// fused: mean[row] and cs[row] in ONE pass over iml. one wave per row.
__global__ void k_mean_cs(const float* __restrict__ iml, const float* __restrict__ alpha,
                          float* __restrict__ mean, float* __restrict__ cs) {
    int w = threadIdx.x >> 6, lane = threadIdx.x & 63;
    int row = blockIdx.x * 4 + w;
    int b = row >> 9;
    const float* p = iml + (size_t)row * KDIM;
    const float* al = alpha + b * KDIM;
    float p0 = p[lane], p1 = p[lane + 64], p2 = p[lane + 128];
    float p3 = (lane < 4) ? p[lane + 192] : 0.f;
    float a3 = (lane < 4) ? al[lane + 192] : 0.f;
    float sm = p0 + p1 + p2 + p3;
    float sc = p0 * al[lane] + p1 * al[lane + 64] + p2 * al[lane + 128] + p3 * a3;
#pragma unroll
    for (int off = 32; off; off >>= 1) { sm += __shfl_down(sm, off); sc += __shfl_down(sc, off); }
    if (lane == 0) { mean[row] = sm * (1.f / 196.f); cs[row] = sc; }
}

// dual dense+relu: z picks (in, W, bias, out). grid (2, 64, 2)
__global__ void k_dense_relu2(const float* __restrict__ in0, const float* __restrict__ in1,
                              const float* __restrict__ W0, const float* __restrict__ W1,
                              const float* __restrict__ bi0, const float* __restrict__ bi1,
                              float* __restrict__ o0, float* __restrict__ o1) {
    int z = blockIdx.z;
    const float* in = z ? in1 : in0;
    const float* W  = z ? W1 : W0;
    const float* bias = z ? bi1 : bi0;
    float* out = z ? o1 : o0;
    int b = blockIdx.y; int j = blockIdx.x * 256 + threadIdx.x;
    __shared__ float xs[512];
    xs[threadIdx.x] = in[b * 512 + threadIdx.x];
    xs[threadIdx.x + 256] = in[b * 512 + threadIdx.x + 256];
    __syncthreads();
    float acc = bias[j];
    const float4* w4 = (const float4*)(W + (size_t)j * 512);
#pragma unroll 4
    for (int i4 = 0; i4 < 128; ++i4) {
        float4 w = w4[i4];
        float4 x = *(const float4*)&xs[i4 * 4];
        acc += w.x * x.x + w.y * x.y + w.z * x.z + w.w * x.w;
    }
    out[(size_t)b * 512 + j] = fmaxf(acc, 0.f);
}

// one-time base-logits GEMM (cs @ fcT_hi), split-K 8; grid (40,8,2)
__global__ void k_gemm_big(const float* __restrict__ A, int astride,
                           const float* __restrict__ Wt, int wn,
                           float* __restrict__ part) {
    int jb = blockIdx.x, kc = blockIdx.y, bh = blockIdx.z;
    int w = threadIdx.x >> 6, lane = threadIdx.x & 63;
    int b0 = __builtin_amdgcn_readfirstlane(bh * 32 + w * 8);
    int k0 = kc * 64;
    int j0 = jb * 256 + lane * 4;
    float4 acc[8];
#pragma unroll
    for (int b = 0; b < 8; ++b) acc[b] = make_float4(0.f, 0.f, 0.f, 0.f);
    const float* wp = Wt + (size_t)k0 * wn + j0;
    const float* xp = A + (size_t)b0 * astride + k0;
#pragma unroll 8
    for (int kk = 0; kk < 64; ++kk) {
        float4 w4 = *(const float4*)(wp + (size_t)kk * wn);
#pragma unroll
        for (int b = 0; b < 8; ++b) {
            float xv = xp[(size_t)b * astride + kk];
            acc[b].x += xv * w4.x; acc[b].y += xv * w4.y;
            acc[b].z += xv * w4.z; acc[b].w += xv * w4.w;
        }
    }
#pragma unroll
    for (int b = 0; b < 8; ++b)
        *(float4*)(part + (size_t)(kc * 64 + b0 + b) * wn + j0) = acc[b];
}

__global__ void k_base_finish(const float* __restrict__ lpart, const float* __restrict__ fc_b,
                              float* __restrict__ base, u64* __restrict__ slots) {
    int b = blockIdx.y; int v = blockIdx.x * 256 + threadIdx.x;
    if (v < V) {
        float s = fc_b[v];
#pragma unroll
        for (int c = 0; c < 8; ++c) s += lpart[(size_t)(c * 64 + b) * VP + v];
        base[(size_t)b * VP + v] = s;
    }
    if (blockIdx.x == 0 && blockIdx.y == 0) {
#pragma unroll
        for (int i = 0; i < 4; ++i) slots[threadIdx.x + i * 256] = 0ull;
    }
}

// ---------------- per-step kernels (3 per step) ----------------

// LSTM partials: grid (16 jb x 4 kc x 8 bh) = 512 blocks; wave = 8b x 128j x K64.
__global__ __launch_bounds__(NT) void k_lstm(
        const float* __restrict__ img, const float* __restrict__ emb,
        const u64* __restrict__ slots, const float* __restrict__ hbuf,
        const float* __restrict__ WcT, float* __restrict__ gpart, int t0) {
    __shared__ float lds[4 * 1024];
    const int jb = blockIdx.x, kc = blockIdx.y, bh = blockIdx.z;
    const int tid = threadIdx.x;
    const int w = __builtin_amdgcn_readfirstlane(tid >> 6), lane = tid & 63;
    const int b0 = bh * 8;
    const int kg0 = kc * 256 + w * 64;
    const float* xp[8];
    if (kg0 < 512) {
        if (t0) {
#pragma unroll
            for (int b = 0; b < 8; ++b) xp[b] = img + (size_t)(b0 + b) * 512 + kg0;
        } else {
#pragma unroll
            for (int b = 0; b < 8; ++b) {
                u32 idx = best_idx_of_slots(slots, b0 + b);
                xp[b] = emb + (size_t)idx * 512 + kg0;
            }
        }
    } else {
#pragma unroll
        for (int b = 0; b < 8; ++b) xp[b] = hbuf + (size_t)(b0 + b) * 512 + (kg0 - 512);
    }
    float2 acc[8];
#pragma unroll
    for (int b = 0; b < 8; ++b) acc[b] = make_float2(0.f, 0.f);
    const float* wp = WcT + (size_t)kg0 * 2048 + jb * 128 + lane * 2;
#pragma unroll 8
    for (int kk = 0; kk < 64; ++kk) {
        float2 wv = *(const float2*)(wp + (size_t)kk * 2048);
#pragma unroll
        for (int b = 0; b < 8; ++b) {
            float xv = xp[b][kk];
            acc[b].x += xv * wv.x; acc[b].y += xv * wv.y;
        }
    }
#pragma unroll
    for (int b = 0; b < 8; ++b)
        *(float2*)&lds[w * 1024 + b * 128 + lane * 2] = acc[b];
    __syncthreads();
    {
        const int bl = tid >> 5;            // 0..7
        const int jj = (tid & 31) * 4;      // 0..124
        float4 s = make_float4(0.f, 0.f, 0.f, 0.f);
#pragma unroll
        for (int wv = 0; wv < 4; ++wv) {
            float4 p = *(const float4*)&lds[wv * 1024 + bl * 128 + jj];
            s.x += p.x; s.y += p.y; s.z += p.z; s.w += p.w;
        }
        *(float4*)&gpart[(size_t)(kc * 64 + b0 + bl) * 2048 + jb * 128 + jj] = s;
    }
}

// gates: reduce 4 partials + biases; h -> hbuf, c in place.
// block 0: out1[t-1] from slots, then zero slots (before k_logits2 refills).
__global__ void k_gates(const float* __restrict__ gpart, const float* __restrict__ bih,
                        const float* __restrict__ bhh, float* __restrict__ hbuf,
                        float* __restrict__ cbuf, u64* __restrict__ slots,
                        float* __restrict__ out1, int t) {
    int e = blockIdx.x * 256 + threadIdx.x;
    int b = e >> 9, jj = e & 511;
    float g[4];
#pragma unroll
    for (int gg = 0; gg < 4; ++gg) {
        int j = jj + gg * 512;
        float s = bih[j] + bhh[j];
#pragma unroll
        for (int kc = 0; kc < 4; ++kc) s += gpart[(size_t)(kc * 64 + b) * 2048 + j];
        g[gg] = s;
    }
    float ig = 1.f / (1.f + expf(-g[0]));
    float fg = 1.f / (1.f + expf(-g[1]));
    float gt = tanhf(g[2]);
    float og = 1.f / (1.f + expf(-g[3]));
    float c = fg * cbuf[e] + ig * gt;
    float h = og * tanhf(c);
    cbuf[e] = c; hbuf[e] = h;
    if (blockIdx.x == 0) {
        if (t > 0 && threadIdx.x < 64)
            out1[threadIdx.x * TSTEPS + (t - 1)] = (float)best_idx_of_slots(slots, threadIdx.x);
        __syncthreads();
        for (int i = threadIdx.x; i < B * SLOTSTRIDE; i += 256) slots[i] = 0ull;
    }
}

// Fused full-K logits: grid (320 jb x 2 bh) = 640 blocks; block = 32b x 32j x K512.
// 4 waves split K (128 each); wave layout: lane = (jg 0..7 [4 j-cols], bg 0..7 [4 b-rows]).
// W traffic/step = 2 x 21MB (32 b rows amortize each W read). 16KB LDS partial reduce;
// epilogue: +base, out0 float4 write, 8-lane argmax reduce, atomicMax -> slots.
__global__ __launch_bounds__(NT) void k_logits2(
        const float* __restrict__ hbuf, const float* __restrict__ fcT,
        const float* __restrict__ base, float* __restrict__ out0,
        u64* __restrict__ slots, int t) {
    __shared__ float lds[4 * 32 * 32];     // [wave][b 0..31][j 0..31]
    const int jb = blockIdx.x, bh = blockIdx.y;
    const int tid = threadIdx.x;
    const int w = __builtin_amdgcn_readfirstlane(tid >> 6), lane = tid & 63;
    const int j0 = jb * 32, b0 = bh * 32;
    const int jg = lane & 7, bg = lane >> 3;
    const int kg0 = w * 128;
    float4 acc[4];
#pragma unroll
    for (int i = 0; i < 4; ++i) acc[i] = make_float4(0.f, 0.f, 0.f, 0.f);
    const float* wp = fcT + (size_t)kg0 * VP + j0 + jg * 4;
    const float* hp = hbuf + (size_t)(b0 + bg * 4) * 512 + kg0;
#pragma unroll 8
    for (int kk = 0; kk < 128; ++kk) {
        float4 w4 = *(const float4*)(wp + (size_t)kk * VP);
        float h0 = hp[kk], h1 = hp[512 + kk], h2 = hp[1024 + kk], h3 = hp[1536 + kk];
        acc[0].x += h0 * w4.x; acc[0].y += h0 * w4.y; acc[0].z += h0 * w4.z; acc[0].w += h0 * w4.w;
        acc[1].x += h1 * w4.x; acc[1].y += h1 * w4.y; acc[1].z += h1 * w4.z; acc[1].w += h1 * w4.w;
        acc[2].x += h2 * w4.x; acc[2].y += h2 * w4.y; acc[2].z += h2 * w4.z; acc[2].w += h2 * w4.w;
        acc[3].x += h3 * w4.x; acc[3].y += h3 * w4.y; acc[3].z += h3 * w4.z; acc[3].w += h3 * w4.w;
    }
#pragma unroll
    for (int i = 0; i < 4; ++i)
        *(float4*)&lds[(w * 32 + bg * 4 + i) * 32 + jg * 4] = acc[i];
    __syncthreads();
    // epilogue: thread = (bl = tid>>3, jg2 = tid&7) -> 4 j-cols of one b-row
    {
        const int bl = tid >> 3;            // 0..31
        const int jg2 = tid & 7;            // 0..7
        const int bgl = b0 + bl;
        const int j = j0 + jg2 * 4;
        float4 s = make_float4(0.f, 0.f, 0.f, 0.f);
#pragma unroll
        for (int wv = 0; wv < 4; ++wv) {
            float4 p = *(const float4*)&lds[(wv * 32 + bl) * 32 + jg2 * 4];
            s.x += p.x; s.y += p.y; s.z += p.z; s.w += p.w;
        }
        float m = -__builtin_inff(); int mi = 0x7fffffff;
        if (j < V) {                        // j mult of 4, V mult of 4 -> all-or-nothing
            float4 bs = *(const float4*)(base + (size_t)bgl * VP + j);
            float4 val = make_float4(s.x + bs.x, s.y + bs.y, s.z + bs.z, s.w + bs.w);
            *(float4*)(out0 + ((size_t)bgl * TSTEPS + t) * V + j) = val;
            m = val.x; mi = j;
            if (val.y > m) { m = val.y; mi = j + 1; }
            if (val.z > m) { m = val.z; mi = j + 2; }
            if (val.w > m) { m = val.w; mi = j + 3; }
        }
#pragma unroll
        for (int mk = 1; mk < 8; mk <<= 1) {
            float ov = __shfl_xor(m, mk);
            int oi = __shfl_xor(mi, mk);
            if (ov > m || (ov == m && oi < mi)) { m = ov; mi = oi; }
        }
        if (jg2 == 0)
            atomicMax(&slots[bgl * SLOTSTRIDE + (jb & 7)], pack_vi(m, mi));
    }
}

__global__ void k_final_out1(const u64* __restrict__ slots, float* __restrict__ out1) {
    int b = threadIdx.x;
    if (b < B) out1[b * TSTEPS + (TSTEPS - 1)] = (float)best_idx_of_slots(slots, b);
}

// ---------------- launch ----------------

extern "C" void kernel_launch(void* const* d_in, const int* in_sizes, int n_in,
                              void* d_out, int out_size, void* d_ws, size_t ws_size,
                              hipStream_t stream) {
    const float* iml   = (const float*)d_in[0];
    const float* img   = (const float*)d_in[1];
    const float* m1w1  = (const float*)d_in[2];
    const float* m1b1  = (const float*)d_in[3];
    const float* m1w2  = (const float*)d_in[4];
    const float* m1b2  = (const float*)d_in[5];
    const float* m2w1  = (const float*)d_in[6];
    const float* m2b1  = (const float*)d_in[7];
    const float* m2w2  = (const float*)d_in[8];
    const float* m2b2  = (const float*)d_in[9];
    const float* wih   = (const float*)d_in[10];
    const float* whh   = (const float*)d_in[11];
    const float* bih   = (const float*)d_in[12];
    const float* bhh   = (const float*)d_in[13];
    const float* attnw = (const float*)d_in[14];
    const float* fcw   = (const float*)d_in[16];
    const float* fcb   = (const float*)d_in[17];
    const float* emb   = (const float*)d_in[18];

    float* out0 = (float*)d_out;
    float* out1 = out0 + (size_t)B * TSTEPS * V;

    float* ws = (float*)d_ws;
    size_t off = 0;
    float* fcT   = ws + off; off += (size_t)512 * VP;
    float* WcT   = ws + off; off += (size_t)1024 * 2048;
    float* bigp  = ws + off; off += (size_t)8 * B * VP;
    float* gpart = ws + off; off += (size_t)4 * B * 2048;
    float* base  = ws + off; off += (size_t)B * VP;
    float* epart = ws + off; off += (size_t)B * 8 * 208;
    float* meanb = ws + off; off += B * 512;
    float* alpha = ws + off; off += B * KDIM;
    float* csb   = ws + off; off += B * 512;
    float* tmp1  = ws + off; off += B * 512;
    float* tmp2  = ws + off; off += B * 512;
    float* hbuf  = ws + off; off += B * 512;
    float* cbuf  = ws + off; off += B * 512;
    u64*   slots = (u64*)(ws + off); off += B * SLOTSTRIDE * 2;

    // ---- precompute (10 dispatches) ----
    k_e_part<<<dim3(64, 8), dim3(256), 0, stream>>>(iml, attnw, epart);
    k_e_softmax<<<dim3(64), dim3(256), 0, stream>>>(epart, alpha);
    k_mean_cs<<<dim3(8192), dim3(256), 0, stream>>>(iml, alpha, meanb, csb);
    k_dense_relu2<<<dim3(2, 64, 2), dim3(256), 0, stream>>>(meanb, meanb, m1w1, m2w1, m1b1, m2b1, tmp1, tmp2);
    k_dense_relu2<<<dim3(2, 64, 2), dim3(256), 0, stream>>>(tmp1, tmp2, m1w2, m2w2, m1b2, m2b2, hbuf, cbuf);
    k_transpose_fc<<<dim3(VP / 32, 16), dim3(32, 8), 0, stream>>>(fcw, fcT, 512);   // hi half
    k_gemm_big<<<dim3(40, 8, 2), dim3(256), 0, stream>>>(csb, 512, fcT, VP, bigp);
    k_base_finish<<<dim3(NVC, 64), dim3(256), 0, stream>>>(bigp, fcb, base, slots);
    k_transpose_fc<<<dim3(VP / 32, 16), dim3(32, 8), 0, stream>>>(fcw, fcT, 0);     // lo half
    k_build_wct<<<dim3(64, 32), dim3(32, 8), 0, stream>>>(wih, whh, WcT);

    // ---- decode loop: 3 kernels/step ----
    for (int t = 0; t < TSTEPS; ++t) {
        k_lstm<<<dim3(16, 4, 8), dim3(NT), 0, stream>>>(img, emb, slots, hbuf, WcT, gpart, (t == 0) ? 1 : 0);
        k_gates<<<dim3(128), dim3(256), 0, stream>>>(gpart, bih, bhh, hbuf, cbuf, slots, out1, t);
        k_logits2<<<dim3(320, 2), dim3(NT), 0, stream>>>(hbuf, fcT, base, out0, slots, t);
    }
    k_final_out1<<<dim3(1), dim3(64), 0, stream>>>(slots, out1);
}

// Round 12
// 1267.410 us; speedup vs baseline: 1.2748x; 1.2748x over previous
//
#include <hip/hip_runtime.h>
#include <hip/hip_bf16.h>

#define B 64
#define KDIM 196
#define H 512
#define V 10000
#define TSTEPS 30
#define VP 10240       // padded V: 40*256
#define NVC 40         // VP/256 chunks
#define NSLOT 8
#define SLOTSTRIDE 16  // u64 per b -> 128B
#define NT 256

typedef unsigned long long u64;
typedef unsigned int u32;

__device__ __forceinline__ u64 pack_vi(float v, int idx) {
    u32 kb = __float_as_uint(v);
    kb = (kb & 0x80000000u) ? ~kb : (kb | 0x80000000u);
    return ((u64)kb << 32) | (u32)(~(u32)idx);
}
__device__ __forceinline__ u32 best_idx_of_slots(const u64* __restrict__ slots, int b) {
    u64 best = slots[b * SLOTSTRIDE];
#pragma unroll
    for (int s = 1; s < NSLOT; ++s) { u64 v = slots[b * SLOTSTRIDE + s]; if (v > best) best = v; }
    u32 idx = ~(u32)best;
    return idx < V ? idx : 0;     // clamp: safety against speculative/poisoned reads
}

// ---------------- precompute kernels ----------------

__global__ void k_transpose_fc(const float* __restrict__ fcw, float* __restrict__ dst, int coloff) {
    __shared__ float tile[32][33];
    int v0 = blockIdx.x * 32, i0 = blockIdx.y * 32;
    int tx = threadIdx.x, ty = threadIdx.y;
#pragma unroll
    for (int r = 0; r < 32; r += 8) {
        int v = v0 + ty + r; int i = i0 + tx;
        tile[ty + r][tx] = (v < V) ? fcw[(size_t)v * 1024 + coloff + i] : 0.f;
    }
    __syncthreads();
#pragma unroll
    for (int r = 0; r < 32; r += 8) {
        int i = i0 + ty + r; int v = v0 + tx;
        dst[(size_t)i * VP + v] = tile[tx][ty + r];
    }
}

__global__ void k_build_wct(const float* __restrict__ wih, const float* __restrict__ whh,
                            float* __restrict__ dst) {
    __shared__ float tile[32][33];
    int j0 = blockIdx.x * 32, i0 = blockIdx.y * 32;
    int tx = threadIdx.x, ty = threadIdx.y;
#pragma unroll
    for (int r = 0; r < 32; r += 8) {
        int j = j0 + ty + r; int i = i0 + tx;
        tile[ty + r][tx] = (i < 512) ? wih[(size_t)j * 512 + i] : whh[(size_t)j * 512 + i - 512];
    }
    __syncthreads();
#pragma unroll
    for (int r = 0; r < 32; r += 8) {
        int i = i0 + ty + r; int j = j0 + tx;
        dst[(size_t)i * 2048 + j] = tile[tx][ty + r];
    }
}

// e partials over h-chunks; grid (64 b, 8 hc)
__global__ void k_e_part(const float* __restrict__ iml, const float* __restrict__ attn_w,
                         float* __restrict__ epart) {
    int b = blockIdx.x, hc = blockIdx.y, t = threadIdx.x;
    __shared__ float wa[64];
    if (t < 64) wa[t] = attn_w[hc * 64 + t];
    __syncthreads();
    if (t < KDIM) {
        const float* p = iml + (size_t)b * 512 * KDIM + (size_t)hc * 64 * KDIM + t;
        float acc = 0.f;
#pragma unroll 8
        for (int h = 0; h < 64; ++h) acc += p[(size_t)h * KDIM] * wa[h];
        epart[(size_t)(b * 8 + hc) * 208 + t] = acc;
    }
}

// reduce 8 partials + softmax over k -> alpha. grid 64
__global__ void k_e_softmax(const float* __restrict__ epart, float* __restrict__ alpha) {
    int b = blockIdx.x, t = threadIdx.x;
    float acc = 0.f;
    if (t < KDIM) {
#pragma unroll
        for (int c = 0; c < 8; ++c) acc += epart[(size_t)(b * 8 + c) * 208 + t];
    }
    __shared__ float red[256];
    red[t] = (t < KDIM) ? acc : -__builtin_inff();
    __syncthreads();
    for (int s = 128; s; s >>= 1) { if (t < s) red[t] = fmaxf(red[t], red[t + s]); __syncthreads(); }
    float mx = red[0];
    __syncthreads();
    float ex = (t < KDIM) ? expf(acc - mx) : 0.f;
    red[t] = ex; __syncthreads();
    for (int s = 128; s; s >>= 1) { if (t < s) red[t] += red[t + s]; __syncthreads(); }
    if (t < KDIM) alpha[b * KDIM + t] = ex / red[0];
}

// fused mean+cs in one iml pass; one wave per row
__global__ void k_mean_cs(const float* __restrict__ iml, const float* __restrict__ alpha,
                          float* __restrict__ mean, float* __restrict__ cs) {
    int w = threadIdx.x >> 6, lane = threadIdx.x & 63;
    int row = blockIdx.x * 4 + w;
    int b = row >> 9;
    const float* p = iml + (size_t)row * KDIM;
    const float* al = alpha + b * KDIM;
    float p0 = p[lane], p1 = p[lane + 64], p2 = p[lane + 128];
    float p3 = (lane < 4) ? p[lane + 192] : 0.f;
    float a3 = (lane < 4) ? al[lane + 192] : 0.f;
    float sm = p0 + p1 + p2 + p3;
    float sc = p0 * al[lane] + p1 * al[lane + 64] + p2 * al[lane + 128] + p3 * a3;
#pragma unroll
    for (int off = 32; off; off >>= 1) { sm += __shfl_down(sm, off); sc += __shfl_down(sc, off); }
    if (lane == 0) { mean[row] = sm * (1.f / 196.f); cs[row] = sc; }
}

// dual dense+relu; grid (2, 64, 2)
__global__ void k_dense_relu2(const float* __restrict__ in0, const float* __restrict__ in1,
                              const float* __restrict__ W0, const float* __restrict__ W1,
                              const float* __restrict__ bi0, const float* __restrict__ bi1,
                              float* __restrict__ o0, float* __restrict__ o1) {
    int z = blockIdx.z;
    const float* in = z ? in1 : in0;
    const float* W  = z ? W1 : W0;
    const float* bias = z ? bi1 : bi0;
    float* out = z ? o1 : o0;
    int b = blockIdx.y; int j = blockIdx.x * 256 + threadIdx.x;
    __shared__ float xs[512];
    xs[threadIdx.x] = in[b * 512 + threadIdx.x];
    xs[threadIdx.x + 256] = in[b * 512 + threadIdx.x + 256];
    __syncthreads();
    float acc = bias[j];
    const float4* w4 = (const float4*)(W + (size_t)j * 512);
#pragma unroll 4
    for (int i4 = 0; i4 < 128; ++i4) {
        float4 w = w4[i4];
        float4 x = *(const float4*)&xs[i4 * 4];
        acc += w.x * x.x + w.y * x.y + w.z * x.z + w.w * x.w;
    }
    out[(size_t)b * 512 + j] = fmaxf(acc, 0.f);
}

// split-K GEMM, r4-champion pattern: scalar (wave-uniform) x loads, 1KB/wave w loads.
// part[(kc*64 + b)*wn + j] = sum_{kk<64} A[b*astride + kc*64+kk] * Wt[(kc*64+kk)*wn + j]
__global__ void k_gemm_big(const float* __restrict__ A, int astride,
                           const float* __restrict__ Wt, int wn,
                           float* __restrict__ part) {
    int jb = blockIdx.x, kc = blockIdx.y, bh = blockIdx.z;
    int w = threadIdx.x >> 6, lane = threadIdx.x & 63;
    int b0 = __builtin_amdgcn_readfirstlane(bh * 32 + w * 8);
    int k0 = kc * 64;
    int j0 = jb * 256 + lane * 4;
    float4 acc[8];
#pragma unroll
    for (int b = 0; b < 8; ++b) acc[b] = make_float4(0.f, 0.f, 0.f, 0.f);
    const float* wp = Wt + (size_t)k0 * wn + j0;
    const float* xp = A + (size_t)b0 * astride + k0;
#pragma unroll 8
    for (int kk = 0; kk < 64; ++kk) {
        float4 w4 = *(const float4*)(wp + (size_t)kk * wn);
#pragma unroll
        for (int b = 0; b < 8; ++b) {
            float xv = xp[(size_t)b * astride + kk];
            acc[b].x += xv * w4.x; acc[b].y += xv * w4.y;
            acc[b].z += xv * w4.z; acc[b].w += xv * w4.w;
        }
    }
#pragma unroll
    for (int b = 0; b < 8; ++b)
        *(float4*)(part + (size_t)(kc * 64 + b0 + b) * wn + j0) = acc[b];
}

__global__ void k_base_finish(const float* __restrict__ lpart, const float* __restrict__ fc_b,
                              float* __restrict__ base, u64* __restrict__ slots) {
    int b = blockIdx.y; int v = blockIdx.x * 256 + threadIdx.x;
    if (v < V) {
        float s = fc_b[v];
#pragma unroll
        for (int c = 0; c < 8; ++c) s += lpart[(size_t)(c * 64 + b) * VP + v];
        base[(size_t)b * VP + v] = s;
    }
    if (blockIdx.x == 0 && blockIdx.y == 0) {
#pragma unroll
        for (int i = 0; i < 4; ++i) slots[threadIdx.x + i * 256] = 0ull;
    }
}

// ---------------- per-step kernels (4 per step) ----------------

// LSTM gates GEMM, r4 pattern with emb-gather folded in (addresses stay wave-uniform).
// grid (8 jb, 16 kc, 2 bh), 256 thr; wave = 8b x 256j x K64. 16 partials.
__global__ void k_lstm_gemm(const float* __restrict__ img, const float* __restrict__ emb,
                            const u64* __restrict__ slots, const float* __restrict__ hbuf,
                            const float* __restrict__ WcT, float* __restrict__ part, int t0) {
    int jb = blockIdx.x, kc = blockIdx.y, bh = blockIdx.z;
    int w = threadIdx.x >> 6, lane = threadIdx.x & 63;
    int b0 = __builtin_amdgcn_readfirstlane(bh * 32 + w * 8);
    int k0 = kc * 64;
    int j0 = jb * 256 + lane * 4;
    const float* xp[8];
    if (k0 < 512) {
        if (t0) {
#pragma unroll
            for (int i = 0; i < 8; ++i) xp[i] = img + (size_t)(b0 + i) * 512 + k0;
        } else {
#pragma unroll
            for (int i = 0; i < 8; ++i) {
                u32 idx = best_idx_of_slots(slots, b0 + i);
                xp[i] = emb + (size_t)idx * 512 + k0;
            }
        }
    } else {
#pragma unroll
        for (int i = 0; i < 8; ++i) xp[i] = hbuf + (size_t)(b0 + i) * 512 + (k0 - 512);
    }
    float4 acc[8];
#pragma unroll
    for (int i = 0; i < 8; ++i) acc[i] = make_float4(0.f, 0.f, 0.f, 0.f);
    const float* wp = WcT + (size_t)k0 * 2048 + j0;
#pragma unroll 8
    for (int kk = 0; kk < 64; ++kk) {
        float4 w4 = *(const float4*)(wp + (size_t)kk * 2048);
#pragma unroll
        for (int i = 0; i < 8; ++i) {
            float xv = xp[i][kk];
            acc[i].x += xv * w4.x; acc[i].y += xv * w4.y;
            acc[i].z += xv * w4.z; acc[i].w += xv * w4.w;
        }
    }
#pragma unroll
    for (int i = 0; i < 8; ++i)
        *(float4*)(part + (size_t)(kc * 64 + b0 + i) * 2048 + j0) = acc[i];
}

// gates: reduce 16 partials + biases; h -> hbuf, c in place.
// block 0: out1[t-1] from slots, then zero slots (before logits_finish refills).
__global__ void k_gates(const float* __restrict__ part, const float* __restrict__ bih,
                        const float* __restrict__ bhh, float* __restrict__ hbuf,
                        float* __restrict__ cbuf, u64* __restrict__ slots,
                        float* __restrict__ out1, int t) {
    int e = blockIdx.x * 256 + threadIdx.x;
    int b = e >> 9, jj = e & 511;
    float g[4];
#pragma unroll
    for (int gg = 0; gg < 4; ++gg) {
        int j = jj + gg * 512;
        float s = bih[j] + bhh[j];
#pragma unroll
        for (int c = 0; c < 16; ++c) s += part[(size_t)(c * 64 + b) * 2048 + j];
        g[gg] = s;
    }
    float ig = 1.f / (1.f + expf(-g[0]));
    float fg = 1.f / (1.f + expf(-g[1]));
    float gt = tanhf(g[2]);
    float og = 1.f / (1.f + expf(-g[3]));
    float c = fg * cbuf[e] + ig * gt;
    float h = og * tanhf(c);
    cbuf[e] = c; hbuf[e] = h;
    if (blockIdx.x == 0) {
        if (t > 0 && threadIdx.x < 64)
            out1[threadIdx.x * TSTEPS + (t - 1)] = (float)best_idx_of_slots(slots, threadIdx.x);
        __syncthreads();
        for (int i = threadIdx.x; i < B * SLOTSTRIDE; i += 256) slots[i] = 0ull;
    }
}

// reduce 8 logits partials + base; write out0; wave-argmax -> slots atomicMax.
// grid (40 vc, 64 b), 256 thr.
__global__ void k_logits_finish(const float* __restrict__ lpart, const float* __restrict__ base,
                                float* __restrict__ out0, u64* __restrict__ slots, int t) {
    int b = blockIdx.y, vc = blockIdx.x, tid = threadIdx.x;
    int lane = tid & 63;
    int v = vc * 256 + tid;
    float val = -__builtin_inff();
    if (v < V) {
        float s = base[(size_t)b * VP + v];
#pragma unroll
        for (int c = 0; c < 8; ++c) s += lpart[(size_t)(c * 64 + b) * VP + v];
        out0[((size_t)b * TSTEPS + t) * V + v] = s;
        val = s;
    }
    float m = val; int mi = (v < V) ? v : 0x7fffffff;
#pragma unroll
    for (int mk = 1; mk < 64; mk <<= 1) {
        float ov = __shfl_xor(m, mk);
        int oi = __shfl_xor(mi, mk);
        if (ov > m || (ov == m && oi < mi)) { m = ov; mi = oi; }
    }
    if (lane == 0) atomicMax(&slots[b * SLOTSTRIDE + (vc & 7)], pack_vi(m, mi));
}

__global__ void k_final_out1(const u64* __restrict__ slots, float* __restrict__ out1) {
    int b = threadIdx.x;
    if (b < B) out1[b * TSTEPS + (TSTEPS - 1)] = (float)best_idx_of_slots(slots, b);
}

// ---------------- launch ----------------

extern "C" void kernel_launch(void* const* d_in, const int* in_sizes, int n_in,
                              void* d_out, int out_size, void* d_ws, size_t ws_size,
                              hipStream_t stream) {
    const float* iml   = (const float*)d_in[0];
    const float* img   = (const float*)d_in[1];
    const float* m1w1  = (const float*)d_in[2];
    const float* m1b1  = (const float*)d_in[3];
    const float* m1w2  = (const float*)d_in[4];
    const float* m1b2  = (const float*)d_in[5];
    const float* m2w1  = (const float*)d_in[6];
    const float* m2b1  = (const float*)d_in[7];
    const float* m2w2  = (const float*)d_in[8];
    const float* m2b2  = (const float*)d_in[9];
    const float* wih   = (const float*)d_in[10];
    const float* whh   = (const float*)d_in[11];
    const float* bih   = (const float*)d_in[12];
    const float* bhh   = (const float*)d_in[13];
    const float* attnw = (const float*)d_in[14];
    const float* fcw   = (const float*)d_in[16];
    const float* fcb   = (const float*)d_in[17];
    const float* emb   = (const float*)d_in[18];

    float* out0 = (float*)d_out;
    float* out1 = out0 + (size_t)B * TSTEPS * V;

    float* ws = (float*)d_ws;
    size_t off = 0;
    float* fcT   = ws + off; off += (size_t)512 * VP;
    float* WcT   = ws + off; off += (size_t)1024 * 2048;
    float* bigp  = ws + off; off += (size_t)8 * B * VP;      // base + logits partials
    float* gpart = ws + off; off += (size_t)16 * B * 2048;   // lstm partials
    float* base  = ws + off; off += (size_t)B * VP;
    float* epart = ws + off; off += (size_t)B * 8 * 208;
    float* meanb = ws + off; off += B * 512;
    float* alpha = ws + off; off += B * KDIM;
    float* csb   = ws + off; off += B * 512;
    float* tmp1  = ws + off; off += B * 512;
    float* tmp2  = ws + off; off += B * 512;
    float* hbuf  = ws + off; off += B * 512;
    float* cbuf  = ws + off; off += B * 512;
    u64*   slots = (u64*)(ws + off); off += B * SLOTSTRIDE * 2;

    // ---- precompute (10 dispatches) ----
    k_e_part<<<dim3(64, 8), dim3(256), 0, stream>>>(iml, attnw, epart);
    k_e_softmax<<<dim3(64), dim3(256), 0, stream>>>(epart, alpha);
    k_mean_cs<<<dim3(8192), dim3(256), 0, stream>>>(iml, alpha, meanb, csb);
    k_dense_relu2<<<dim3(2, 64, 2), dim3(256), 0, stream>>>(meanb, meanb, m1w1, m2w1, m1b1, m2b1, tmp1, tmp2);
    k_dense_relu2<<<dim3(2, 64, 2), dim3(256), 0, stream>>>(tmp1, tmp2, m1w2, m2w2, m1b2, m2b2, hbuf, cbuf);
    k_transpose_fc<<<dim3(VP / 32, 16), dim3(32, 8), 0, stream>>>(fcw, fcT, 512);   // hi half
    k_gemm_big<<<dim3(40, 8, 2), dim3(256), 0, stream>>>(csb, 512, fcT, VP, bigp);
    k_base_finish<<<dim3(NVC, 64), dim3(256), 0, stream>>>(bigp, fcb, base, slots);
    k_transpose_fc<<<dim3(VP / 32, 16), dim3(32, 8), 0, stream>>>(fcw, fcT, 0);     // lo half
    k_build_wct<<<dim3(64, 32), dim3(32, 8), 0, stream>>>(wih, whh, WcT);

    // ---- decode loop: 4 kernels/step ----
    for (int t = 0; t < TSTEPS; ++t) {
        k_lstm_gemm<<<dim3(8, 16, 2), dim3(256), 0, stream>>>(img, emb, slots, hbuf, WcT, gpart, (t == 0) ? 1 : 0);
        k_gates<<<dim3(128), dim3(256), 0, stream>>>(gpart, bih, bhh, hbuf, cbuf, slots, out1, t);
        k_gemm_big<<<dim3(40, 8, 2), dim3(256), 0, stream>>>(hbuf, 512, fcT, VP, bigp);
        k_logits_finish<<<dim3(NVC, 64), dim3(256), 0, stream>>>(bigp, base, out0, slots, t);
    }
    k_final_out1<<<dim3(1), dim3(64), 0, stream>>>(slots, out1);
}